// Round 12
// baseline (784.367 us; speedup 1.0000x reference)
//
#include <hip/hip_runtime.h>
#include <cstddef>
#include <cstdint>
#include <math.h>

#define N_NODES 50000
#define N_EDGES 1600000
#define IN_C 512
#define HID_C 256
#define OUT_C 50
#define PAD_C 64
#define NUM_LAYERS 10
#define NBUCK 98          // ceil(50000/512) row-buckets
#define BSHIFT 9          // 512 rows per bucket
#define BCAP 20480        // mean 16327 + 32 sigma — overflow unreachable
#define PHB_CHUNK 8192    // edges per block in bucket_scatter
#define PHB_BLOCKS 196    // ceil(N_EDGES / PHB_CHUNK)
#define TW_BLOCKS 128     // transpose_w1: 16 k-tiles x 8 n-tiles
#define PW_BLOCKS 64      // pad_w2: 16384 / 256
#define GEMM_BLOCKS 782   // ceil(N_NODES / 64)

typedef __attribute__((ext_vector_type(8))) short short8;    // 8 bf16 (4 VGPRs)
typedef __attribute__((ext_vector_type(4))) float floatx4;   // MFMA C/D frag
typedef __attribute__((ext_vector_type(2))) float floatx2;

__device__ inline unsigned short f2bf(float f) {             // RNE fp32->bf16
    unsigned int u = __float_as_uint(f);
    u += 0x7fffu + ((u >> 16) & 1u);
    return (unsigned short)(u >> 16);
}

__device__ inline unsigned cvtpk(float lo, float hi) {       // 2xf32 -> packed bf16x2 (RNE)
    unsigned r;
    asm("v_cvt_pk_bf16_f32 %0, %1, %2" : "=v"(r) : "v"(lo), "v"(hi));
    return r;
}

__device__ inline short8 pack_bf16x8(float4 lo, float4 hi) {
    union { unsigned u[4]; short8 s; } r;
    r.u[0] = cvtpk(lo.x, lo.y);
    r.u[1] = cvtpk(lo.z, lo.w);
    r.u[2] = cvtpk(hi.x, hi.y);
    r.u[3] = cvtpk(hi.z, hi.w);
    return r.s;
}

// ---- fp8 e4m3 (OCP) helpers: HW cvt, saturating on pack ----
__device__ inline void fp8x4_fma(float wgt, unsigned w, float* acc) {
    floatx2 lo = __builtin_amdgcn_cvt_pk_f32_fp8(w, false);   // bytes 0,1
    floatx2 hi = __builtin_amdgcn_cvt_pk_f32_fp8(w, true);    // bytes 2,3
    acc[0] = fmaf(wgt, lo[0], acc[0]);
    acc[1] = fmaf(wgt, lo[1], acc[1]);
    acc[2] = fmaf(wgt, hi[0], acc[2]);
    acc[3] = fmaf(wgt, hi[1], acc[3]);
}
__device__ inline void fp8_fma16(float* acc, float wgt, uint4 hv) {
    fp8x4_fma(wgt, hv.x, acc + 0);
    fp8x4_fma(wgt, hv.y, acc + 4);
    fp8x4_fma(wgt, hv.z, acc + 8);
    fp8x4_fma(wgt, hv.w, acc + 12);
}
__device__ inline unsigned pack_fp8x4(float a, float b, float c, float d) {
    int r = 0;
    r = __builtin_amdgcn_cvt_pk_fp8_f32(a, b, r, false);
    r = __builtin_amdgcn_cvt_pk_fp8_f32(c, d, r, true);
    return (unsigned)r;
}

// async 16B global->LDS (LDS dest is wave-uniform base + lane*16)
#define ASYNC16(g, l)                                                     \
    __builtin_amdgcn_global_load_lds(                                     \
        (const __attribute__((address_space(1))) void*)(g),               \
        (__attribute__((address_space(3))) void*)(l), 16, 0, 0)

#define WAITCNT6() asm volatile("s_waitcnt vmcnt(6)" ::: "memory")
#define WAITCNT0() asm volatile("s_waitcnt vmcnt(0)" ::: "memory")
#define SBAR()     __builtin_amdgcn_s_barrier()

// ---------------------------------------------------------------------------
// K1 prep_fused (R10-verified): three independent prep kernels, block ranges.
// ---------------------------------------------------------------------------
__global__ __launch_bounds__(256) void prep_fused(const int* __restrict__ erow,
                                                  const int* __restrict__ ecol,
                                                  const float* __restrict__ ew,
                                                  int* __restrict__ bfill,
                                                  uint2* __restrict__ buckets,
                                                  const float* __restrict__ W1,
                                                  unsigned short* __restrict__ Wt,
                                                  const float* __restrict__ W2,
                                                  const float* __restrict__ b2,
                                                  unsigned short* __restrict__ Wpt,
                                                  float* __restrict__ bp) {
    __shared__ int  lcnt[NBUCK];
    __shared__ int  lbase[NBUCK];
    __shared__ float tile[32][33];
    const int bid = blockIdx.x;
    const int t = threadIdx.x;

    if (bid < PHB_BLOCKS) {
        // ---- bucket_scatter ----
        for (int b = t; b < NBUCK; b += 256) lcnt[b] = 0;
        __syncthreads();
        const int e0 = bid * PHB_CHUNK;
        const int e1 = min(e0 + PHB_CHUNK, N_EDGES);
        for (int e = e0 + t; e < e1; e += 256)
            atomicAdd(&lcnt[erow[e] >> BSHIFT], 1);
        __syncthreads();
        for (int b = t; b < NBUCK; b += 256) {
            lbase[b] = atomicAdd(&bfill[b], lcnt[b]);
            lcnt[b] = 0;
        }
        __syncthreads();
        for (int e = e0 + t; e < e1; e += 256) {
            int r = erow[e];
            int b = r >> BSHIFT;
            int o = atomicAdd(&lcnt[b], 1);
            int idx = lbase[b] + o;
            if (idx < BCAP) {   // BCAP = mean + 32 sigma: always true
                unsigned packed = ((unsigned)(r - (b << BSHIFT)) << 17) | (unsigned)ecol[e];
                buckets[(size_t)b * BCAP + idx] = make_uint2(packed, __float_as_uint(ew[e]));
            }
        }
    } else if (bid < PHB_BLOCKS + TW_BLOCKS) {
        // ---- transpose_w1 ----
        int tb = bid - PHB_BLOCKS;
        int bx = tb & 15;              // k-tile (16)
        int by = tb >> 4;              // n-tile (8)
        int tx = t & 31, ty = t >> 5;  // 32 x 8
#pragma unroll
        for (int i = 0; i < 32; i += 8)
            tile[ty + i][tx] = W1[(bx * 32 + ty + i) * HID_C + by * 32 + tx];
        __syncthreads();
#pragma unroll
        for (int i = 0; i < 32; i += 8)
            Wt[(size_t)(by * 32 + ty + i) * IN_C + bx * 32 + tx] = f2bf(tile[tx][ty + i]);
    } else {
        // ---- pad_w2 ----
        int idx = (bid - PHB_BLOCKS - TW_BLOCKS) * 256 + t;
        if (idx < PAD_C * HID_C) {
            int n = idx >> 8, k = idx & 255;
            float v = (n < OUT_C) ? W2[k * OUT_C + n] : 0.f;
            Wpt[idx] = f2bf(v);
        }
        if (idx < PAD_C) bp[idx] = (idx < OUT_C) ? b2[idx] : 0.f;
    }
}

__global__ __launch_bounds__(128) void bucket_scan(const int* __restrict__ bfill,
                                                   int* __restrict__ bbase,
                                                   int* __restrict__ rowptr) {
    __shared__ int sd[128];
    int t = threadIdx.x;
    int v = (t < NBUCK) ? min(bfill[t], BCAP) : 0;
    sd[t] = v;
    __syncthreads();
    for (int off = 1; off < 128; off <<= 1) {
        int x = (t >= off) ? sd[t - off] : 0;
        __syncthreads();
        sd[t] += x;
        __syncthreads();
    }
    if (t < NBUCK) bbase[t] = sd[t] - v;
    if (t == NBUCK - 1) {
        bbase[NBUCK] = sd[t];
        rowptr[N_NODES] = sd[t];
    }
}

// ---------------------------------------------------------------------------
// K2 csr_gemm_fused (R10/R11-verified, 84-88us): bucket_csr [0,98) concurrent
// with gemm [98,880). v2 delta: epilogue also computes global absmax(h0) via
// wave-reduce + atomicMax into amax[0] (fp8 scale chain anchor).
// ---------------------------------------------------------------------------
__global__ __launch_bounds__(256) void csr_gemm_fused(
        // csr part
        const uint2* __restrict__ buckets, const int* __restrict__ bfill,
        const int* __restrict__ bbase, int* __restrict__ rowptr,
        uint2* __restrict__ edges,
        // gemm part
        const float* __restrict__ A, const unsigned short* __restrict__ Wt,
        const float* __restrict__ b1, const unsigned short* __restrict__ Wpt,
        const float* __restrict__ bp, unsigned short* __restrict__ h0b,
        unsigned* __restrict__ amax) {
    __shared__ __align__(16) char smem[73728];
    const int bid = blockIdx.x;
    const int tid = threadIdx.x;

    if (bid < NBUCK) {
        // ================= bucket_csr =================
        int* hist = (int*)smem;               // 512 ints
        int* excl = (int*)(smem + 2048);      // 512 ints
        int* psum = (int*)(smem + 4096);      // 256 ints
        const int b = bid;
        const int t = tid;
        const int n = min(bfill[b], BCAP);
        const uint2* bk = buckets + (size_t)b * BCAP;

        hist[t] = 0; hist[t + 256] = 0;
        __syncthreads();
        for (int i = t; i < n; i += 256)
            atomicAdd(&hist[bk[i].x >> 17], 1);
        __syncthreads();
        int a0 = hist[2 * t], a1 = hist[2 * t + 1];
        psum[t] = a0 + a1;
        __syncthreads();
        for (int off = 1; off < 256; off <<= 1) {
            int x = (t >= off) ? psum[t - off] : 0;
            __syncthreads();
            psum[t] += x;
            __syncthreads();
        }
        int pe = psum[t] - (a0 + a1);
        excl[2 * t] = pe;
        excl[2 * t + 1] = pe + a0;
        __syncthreads();
        const int base = bbase[b];
#pragma unroll
        for (int k = 0; k < 2; ++k) {
            int lr = t + k * 256;
            int r = (b << BSHIFT) + lr;
            if (r < N_NODES) rowptr[r] = base + excl[lr];
        }
        hist[t] = 0; hist[t + 256] = 0;
        __syncthreads();
        for (int i = t; i < n; i += 256) {
            uint2 ed = bk[i];
            int lr = ed.x >> 17;
            int pos = base + excl[lr] + atomicAdd(&hist[lr], 1);
            edges[pos] = make_uint2(ed.x & 0x1FFFFu, ed.y);
        }
        return;
    }

    // ================= gemm1_fused (R9 body, verified) =================
    float*          Ab[3] = {(float*)smem,
                             (float*)(smem + 24576),
                             (float*)(smem + 49152)};
    unsigned short* Bb[3] = {(unsigned short*)(smem + 8192),
                             (unsigned short*)(smem + 32768),
                             (unsigned short*)(smem + 57344)};
    unsigned short* Hs = (unsigned short*)smem;    // [64][264] bf16 (reused)
    const int HS_LD = 264;

    const int wave = tid >> 6, lane = tid & 63;
    const int quad = lane >> 4, l16 = lane & 15;
    const int m0 = (bid - NBUCK) * 64;
    const int wm = (wave >> 1) * 32;               // row offset of this wave
    const int wn = (wave & 1) * 128;               // col offset of this wave

    floatx4 acc[2][8];
#pragma unroll
    for (int i = 0; i < 2; ++i)
#pragma unroll
        for (int j = 0; j < 8; ++j) acc[i][j] = (floatx4){0.f, 0.f, 0.f, 0.f};

    auto stage = [&](int bi, int ks) {
        const int k0 = ks << 5;
#pragma unroll
        for (int j = 0; j < 2; ++j) {
            int slot = tid + j * 256;
            int r = slot >> 3, c = slot & 7;
            int gr = m0 + r;
            if (gr >= N_NODES) gr = N_NODES - 1;   // clamp: finite garbage, masked later
            const float* src = A + (size_t)gr * IN_C + k0 + ((c ^ (r & 7)) << 2);
            ASYNC16(src, Ab[bi] + (slot << 2));
        }
#pragma unroll
        for (int j = 0; j < 4; ++j) {              // row-major: slot=(n,c), 16B chunks
            int slot = tid + j * 256;              // 0..1023
            int n = slot >> 2, c = slot & 3;
            int cs = c ^ ((n >> 1) & 3);           // source-side swizzle (64B-local)
            const unsigned short* src = Wt + (size_t)n * IN_C + k0 + (cs << 3);
            ASYNC16(src, Bb[bi] + (slot << 3));    // LDS linear in slot
        }
    };

    auto compute = [&](int bi) {
        const float* As_ = Ab[bi];
        const unsigned short* Bs_ = Bb[bi];
        short8 bfr[8], afr[2];
#pragma unroll
        for (int nt = 0; nt < 8; ++nt) {
            int n  = wn + nt * 16 + l16;
            int cq = quad ^ ((n >> 1) & 3);        // read-side swizzle (same involution)
            bfr[nt] = *(const short8*)&Bs_[(n << 5) + (cq << 3)];
        }
#pragma unroll
        for (int mt = 0; mt < 2; ++mt) {
            int r  = wm + mt * 16 + l16;
            int rx = r & 7;
            float4 lo = *(const float4*)&As_[(r << 5) + (((2 * quad)     ^ rx) << 2)];
            float4 hi = *(const float4*)&As_[(r << 5) + (((2 * quad + 1) ^ rx) << 2)];
            afr[mt] = pack_bf16x8(lo, hi);
        }
#pragma unroll
        for (int mt = 0; mt < 2; ++mt)
#pragma unroll
            for (int nt = 0; nt < 8; ++nt)
                acc[mt][nt] = __builtin_amdgcn_mfma_f32_16x16x32_bf16(afr[mt], bfr[nt],
                                                                      acc[mt][nt], 0, 0, 0);
    };

    // --- pipelined main loop: 16 K-steps, 3 buffers, depth-2 prefetch ------
    stage(0, 0);
    stage(1, 1);
#pragma unroll
    for (int ks = 0; ks < 14; ++ks) {
        WAITCNT6();                    // buf ks%3 landed (only ks+1's 6 in flight)
        SBAR();                        // all waves: buf ks ready; buf (ks+2)%3 free
        stage((ks + 2) % 3, ks + 2);   // async; needed 2 iterations from now
        compute(ks % 3);
    }
    WAITCNT6(); SBAR(); compute(2);    // ks=14
    WAITCNT0(); SBAR(); compute(0);    // ks=15 (drain)
    __syncthreads();                   // before Hs overlays buffers

    // --- stage relu(h + b1) to LDS bf16 (row = quad*4+r, col = l16 map) ----
#pragma unroll
    for (int nt = 0; nt < 8; ++nt) {
        int n = wn + nt * 16 + l16;
        float bn = b1[n];
#pragma unroll
        for (int mt = 0; mt < 2; ++mt)
#pragma unroll
            for (int r = 0; r < 4; ++r) {
                float v = acc[mt][nt][r] + bn;
                v = v > 0.f ? v : 0.f;
                Hs[(wm + mt * 16 + quad * 4 + r) * HS_LD + n] = f2bf(v);
            }
    }
    __syncthreads();

    // --- fused GEMM2: h0[64,64] = Hs[64,256] @ Wpt^T + bp ------------------
    floatx4 acc2[4];
#pragma unroll
    for (int nt = 0; nt < 4; ++nt) acc2[nt] = (floatx4){0.f, 0.f, 0.f, 0.f};
    const int hrow = (wave << 4) + l16;
#pragma unroll
    for (int k2 = 0; k2 < 8; ++k2) {
        short8 haf = *(const short8*)&Hs[hrow * HS_LD + (k2 << 5) + (quad << 3)];
#pragma unroll
        for (int nt = 0; nt < 4; ++nt) {
            short8 bf = *(const short8*)&Wpt[(size_t)((nt << 4) + l16) * HID_C + (k2 << 5) + (quad << 3)];
            acc2[nt] = __builtin_amdgcn_mfma_f32_16x16x32_bf16(haf, bf, acc2[nt], 0, 0, 0);
        }
    }
    float vmax = 0.f;
#pragma unroll
    for (int nt = 0; nt < 4; ++nt) {
        int c = (nt << 4) + l16;
        float bn = bp[c];
#pragma unroll
        for (int r = 0; r < 4; ++r) {
            int row = m0 + (wave << 4) + (quad << 2) + r;
            float v = acc2[nt][r] + bn;
            vmax = fmaxf(vmax, fabsf(v));
            if (row < N_NODES)
                h0b[(size_t)row * PAD_C + c] = f2bf(v);
        }
    }
    // global absmax(h0) -> amax[0]  (clamped OOB rows duplicate real rows: harmless)
#pragma unroll
    for (int s = 1; s < 64; s <<= 1) vmax = fmaxf(vmax, __shfl_xor(vmax, s, 64));
    if (lane == 0) atomicMax(&amax[0], __float_as_uint(vmax));
}

// ---------------------------------------------------------------------------
// fp8 scale chain: t_l = h_l * s_l with s_l = 4/amax[l-1] (l>=1); amax[l] =
// absmax(h_l), accumulated by the kernel that PRODUCES h_l via guarded
// atomicMax. Worst-case growth <= 0.9*maxdeg*maxw ~ 60 < 64 => |t| <= 256
// < 448 (e4m3 max): overflow impossible. Reader recomputes the writer's
// scale from the same amax entry -> deterministic consistency.
// ---------------------------------------------------------------------------

// Layer 0: bf16 gather from h0b (R11-proven geometry: 8 slots x 8 lanes,
// 128B rows), writes fp8 t1 (scale 4/amax[0]) + amax[1].
__device__ inline void edge_fma(float* acc, float wgt, uint4 hv) {
    acc[0] = fmaf(wgt, __uint_as_float(hv.x << 16),         acc[0]);
    acc[1] = fmaf(wgt, __uint_as_float(hv.x & 0xffff0000u), acc[1]);
    acc[2] = fmaf(wgt, __uint_as_float(hv.y << 16),         acc[2]);
    acc[3] = fmaf(wgt, __uint_as_float(hv.y & 0xffff0000u), acc[3]);
    acc[4] = fmaf(wgt, __uint_as_float(hv.z << 16),         acc[4]);
    acc[5] = fmaf(wgt, __uint_as_float(hv.z & 0xffff0000u), acc[5]);
    acc[6] = fmaf(wgt, __uint_as_float(hv.w << 16),         acc[6]);
    acc[7] = fmaf(wgt, __uint_as_float(hv.w & 0xffff0000u), acc[7]);
}

__global__ __launch_bounds__(256, 8) void prop0(const int* __restrict__ rowptr,
                                                const uint2* __restrict__ edges,
                                                const unsigned short* __restrict__ h0b,
                                                unsigned* __restrict__ amax,
                                                unsigned char* __restrict__ tout) {
    int wid = (blockIdx.x * blockDim.x + threadIdx.x) >> 6;
    if (wid >= N_NODES) return;
    int lane = threadIdx.x & 63;
    int slot = lane >> 3;
    int lc   = lane & 7;
    int s = rowptr[wid], e = rowptr[wid + 1];

    float acc0[8], acc1[8];
#pragma unroll
    for (int k = 0; k < 8; ++k) { acc0[k] = 0.f; acc1[k] = 0.f; }

    int i = s;
    for (; i + 32 <= e; i += 32) {
        uint2 cw0 = edges[i + slot];
        uint2 cw1 = edges[i + 8 + slot];
        uint2 cw2 = edges[i + 16 + slot];
        uint2 cw3 = edges[i + 24 + slot];
        uint4 hv0 = *(const uint4*)((const char*)h0b + ((size_t)cw0.x << 7) + lc * 16);
        uint4 hv1 = *(const uint4*)((const char*)h0b + ((size_t)cw1.x << 7) + lc * 16);
        uint4 hv2 = *(const uint4*)((const char*)h0b + ((size_t)cw2.x << 7) + lc * 16);
        uint4 hv3 = *(const uint4*)((const char*)h0b + ((size_t)cw3.x << 7) + lc * 16);
        edge_fma(acc0, __uint_as_float(cw0.y), hv0);
        edge_fma(acc1, __uint_as_float(cw1.y), hv1);
        edge_fma(acc0, __uint_as_float(cw2.y), hv2);
        edge_fma(acc1, __uint_as_float(cw3.y), hv3);
    }
    for (; i + 16 <= e; i += 16) {
        uint2 cw0 = edges[i + slot];
        uint2 cw1 = edges[i + 8 + slot];
        uint4 hv0 = *(const uint4*)((const char*)h0b + ((size_t)cw0.x << 7) + lc * 16);
        uint4 hv1 = *(const uint4*)((const char*)h0b + ((size_t)cw1.x << 7) + lc * 16);
        edge_fma(acc0, __uint_as_float(cw0.y), hv0);
        edge_fma(acc1, __uint_as_float(cw1.y), hv1);
    }
    for (; i < e; i += 8) {
        int idx = i + slot;
        uint2 cw = (idx < e) ? edges[idx] : make_uint2(0u, 0u);
        float wgt = (idx < e) ? __uint_as_float(cw.y) : 0.f;
        uint4 hv = *(const uint4*)((const char*)h0b + ((size_t)cw.x << 7) + lc * 16);
        edge_fma(acc0, wgt, hv);
    }

    float r[8];
#pragma unroll
    for (int k = 0; k < 8; ++k) {
        float v = acc0[k] + acc1[k];
        v += __shfl_xor(v, 8, 64);
        v += __shfl_xor(v, 16, 64);
        v += __shfl_xor(v, 32, 64);
        r[k] = v;
    }

    uint4 h0v = *(const uint4*)((const char*)h0b + ((size_t)wid << 7) + lc * 16);
    float h0e[8];
    h0e[0] = __uint_as_float(h0v.x << 16);
    h0e[1] = __uint_as_float(h0v.x & 0xffff0000u);
    h0e[2] = __uint_as_float(h0v.y << 16);
    h0e[3] = __uint_as_float(h0v.y & 0xffff0000u);
    h0e[4] = __uint_as_float(h0v.z << 16);
    h0e[5] = __uint_as_float(h0v.z & 0xffff0000u);
    h0e[6] = __uint_as_float(h0v.w << 16);
    h0e[7] = __uint_as_float(h0v.w & 0xffff0000u);
#pragma unroll
    for (int k = 0; k < 8; ++k) r[k] = 0.9f * r[k] + 0.1f * h0e[k];

    // write fp8 t1 (scale 4/amax[0])
    float s_out = 4.0f / __uint_as_float(amax[0]);
    if (slot == 0) {
        uint2 u;
        u.x = pack_fp8x4(r[0] * s_out, r[1] * s_out, r[2] * s_out, r[3] * s_out);
        u.y = pack_fp8x4(r[4] * s_out, r[5] * s_out, r[6] * s_out, r[7] * s_out);
        *(uint2*)(tout + (size_t)wid * 64 + lc * 8) = u;
    }
    // amax[1] (guarded atomic: few actual atomics)
    float vmax = 0.f;
#pragma unroll
    for (int k = 0; k < 8; ++k) vmax = fmaxf(vmax, fabsf(r[k]));
    vmax = fmaxf(vmax, __shfl_xor(vmax, 1, 64));
    vmax = fmaxf(vmax, __shfl_xor(vmax, 2, 64));
    vmax = fmaxf(vmax, __shfl_xor(vmax, 4, 64));
    if (lane == 0) {
        unsigned cur = __hip_atomic_load(&amax[1], __ATOMIC_RELAXED, __HIP_MEMORY_SCOPE_AGENT);
        if (vmax > __uint_as_float(cur)) atomicMax(&amax[1], __float_as_uint(vmax));
    }
}

// Layers 1..9: fp8 gather (16 slots x 4 lanes, 64B rows -> 16 edges/instr,
// table 3.2MB fits per-XCD L2). LAST fuses log_softmax.
template <bool LAST>
__global__ __launch_bounds__(256, 8) void prop_fp8(const int* __restrict__ rowptr,
                                                   const uint2* __restrict__ edges,
                                                   const unsigned char* __restrict__ tin,
                                                   const unsigned short* __restrict__ h0b,
                                                   unsigned* __restrict__ amax,
                                                   const int l,
                                                   unsigned char* __restrict__ tout,
                                                   float* __restrict__ out_f) {
    int wid = (blockIdx.x * blockDim.x + threadIdx.x) >> 6;
    if (wid >= N_NODES) return;
    int lane = threadIdx.x & 63;
    int slot = lane >> 2;          // 16 slots (one edge each)
    int lc2  = lane & 3;           // 4 lanes/slot, 16B = 16 fp8 channels each
    int s = rowptr[wid], e = rowptr[wid + 1];

    float acc[16];
#pragma unroll
    for (int k = 0; k < 16; ++k) acc[k] = 0.f;

    int i = s;
    for (; i + 32 <= e; i += 32) {
        uint2 cw0 = edges[i + slot];
        uint2 cw1 = edges[i + 16 + slot];
        uint4 hv0 = *(const uint4*)(tin + ((size_t)cw0.x << 6) + lc2 * 16);
        uint4 hv1 = *(const uint4*)(tin + ((size_t)cw1.x << 6) + lc2 * 16);
        fp8_fma16(acc, __uint_as_float(cw0.y), hv0);
        fp8_fma16(acc, __uint_as_float(cw1.y), hv1);
    }
    for (; i < e; i += 16) {
        int idx = i + slot;
        uint2 cw = (idx < e) ? edges[idx] : make_uint2(0u, 0u);
        float wgt = (idx < e) ? __uint_as_float(cw.y) : 0.f;
        uint4 hv = *(const uint4*)(tin + ((size_t)cw.x << 6) + lc2 * 16);
        fp8_fma16(acc, wgt, hv);
    }

    const float inv_sin = __uint_as_float(amax[l - 1]) * 0.25f;  // 1/s_in

    float r[16];
#pragma unroll
    for (int k = 0; k < 16; ++k) {
        float v = acc[k];
        v += __shfl_xor(v, 4, 64);
        v += __shfl_xor(v, 8, 64);
        v += __shfl_xor(v, 16, 64);
        v += __shfl_xor(v, 32, 64);
        r[k] = v;
    }

    // residual: 16 bf16 channels from h0b
    uint4 ha = *(const uint4*)((const char*)h0b + ((size_t)wid << 7) + lc2 * 32);
    uint4 hb = *(const uint4*)((const char*)h0b + ((size_t)wid << 7) + lc2 * 32 + 16);
    float h0e[16];
    h0e[0]  = __uint_as_float(ha.x << 16); h0e[1]  = __uint_as_float(ha.x & 0xffff0000u);
    h0e[2]  = __uint_as_float(ha.y << 16); h0e[3]  = __uint_as_float(ha.y & 0xffff0000u);
    h0e[4]  = __uint_as_float(ha.z << 16); h0e[5]  = __uint_as_float(ha.z & 0xffff0000u);
    h0e[6]  = __uint_as_float(ha.w << 16); h0e[7]  = __uint_as_float(ha.w & 0xffff0000u);
    h0e[8]  = __uint_as_float(hb.x << 16); h0e[9]  = __uint_as_float(hb.x & 0xffff0000u);
    h0e[10] = __uint_as_float(hb.y << 16); h0e[11] = __uint_as_float(hb.y & 0xffff0000u);
    h0e[12] = __uint_as_float(hb.z << 16); h0e[13] = __uint_as_float(hb.z & 0xffff0000u);
    h0e[14] = __uint_as_float(hb.w << 16); h0e[15] = __uint_as_float(hb.w & 0xffff0000u);
#pragma unroll
    for (int k = 0; k < 16; ++k) r[k] = 0.9f * inv_sin * r[k] + 0.1f * h0e[k];

    if (!LAST) {
        float s_out = 4.0f / __uint_as_float(amax[l]);
        if (slot == 0) {
            uint4 u;
            u.x = pack_fp8x4(r[0]*s_out,  r[1]*s_out,  r[2]*s_out,  r[3]*s_out);
            u.y = pack_fp8x4(r[4]*s_out,  r[5]*s_out,  r[6]*s_out,  r[7]*s_out);
            u.z = pack_fp8x4(r[8]*s_out,  r[9]*s_out,  r[10]*s_out, r[11]*s_out);
            u.w = pack_fp8x4(r[12]*s_out, r[13]*s_out, r[14]*s_out, r[15]*s_out);
            *(uint4*)(tout + (size_t)wid * 64 + lc2 * 16) = u;
        }
        float vmax = 0.f;
#pragma unroll
        for (int k = 0; k < 16; ++k) vmax = fmaxf(vmax, fabsf(r[k]));
        vmax = fmaxf(vmax, __shfl_xor(vmax, 1, 64));
        vmax = fmaxf(vmax, __shfl_xor(vmax, 2, 64));
        if (lane == 0) {
            unsigned cur = __hip_atomic_load(&amax[l + 1], __ATOMIC_RELAXED,
                                             __HIP_MEMORY_SCOPE_AGENT);
            if (vmax > __uint_as_float(cur)) atomicMax(&amax[l + 1], __float_as_uint(vmax));
        }
    } else {
        const int nval = (lc2 == 3) ? 2 : 16;    // ch = lc2*16+k valid if < 50
        float m = -INFINITY;
#pragma unroll
        for (int k = 0; k < 16; ++k) if (k < nval) m = fmaxf(m, r[k]);
        m = fmaxf(m, __shfl_xor(m, 1, 64));
        m = fmaxf(m, __shfl_xor(m, 2, 64));
        float ss = 0.f;
#pragma unroll
        for (int k = 0; k < 16; ++k) if (k < nval) ss += __expf(r[k] - m);
        ss += __shfl_xor(ss, 1, 64);
        ss += __shfl_xor(ss, 2, 64);
        float lse = __logf(ss);
        if (slot == 0) {
#pragma unroll
            for (int k = 0; k < 16; ++k)
                if (k < nval)
                    out_f[(size_t)wid * OUT_C + lc2 * 16 + k] = (r[k] - m) - lse;
        }
    }
}

// ---------------------------------------------------------------------------
extern "C" void kernel_launch(void* const* d_in, const int* in_sizes, int n_in,
                              void* d_out, int out_size, void* d_ws, size_t ws_size,
                              hipStream_t stream) {
    const float* x    = (const float*)d_in[0];
    const int*   erow = (const int*)d_in[1];
    const int*   ecol = (const int*)d_in[2];
    const float* ew   = (const float*)d_in[3];
    const float* W1   = (const float*)d_in[4];
    const float* b1   = (const float*)d_in[5];
    const float* W2   = (const float*)d_in[6];
    const float* b2   = (const float*)d_in[7];
    float* out = (float*)d_out;

    char* p = (char*)d_ws;
    auto alloc = [&](size_t bytes) {
        char* r = p;
        p += (bytes + 255) & ~(size_t)255;
        return r;
    };
    char*  scratch = alloc((size_t)NBUCK * BCAP * 8);             // 16.1 MB (buckets / ta / tb)
    unsigned short* h0b = (unsigned short*)alloc((size_t)N_NODES * PAD_C * 2); // 6.4 MB
    uint2* edges  = (uint2*)alloc((size_t)N_EDGES * 8);           // 12.8 MB packed CSR
    int*   rowptr = (int*)alloc((size_t)(N_NODES + 1) * 4);
    int*   bfill  = (int*)alloc((size_t)NBUCK * 4);
    int*   bbase  = (int*)alloc((size_t)(NBUCK + 1) * 4);
    unsigned* amax = (unsigned*)alloc(64);                        // absmax chain amax[0..10]
    float* bp     = (float*)alloc((size_t)PAD_C * 4);
    unsigned short* Wt  = (unsigned short*)alloc((size_t)HID_C * IN_C * 2);
    unsigned short* Wpt = (unsigned short*)alloc((size_t)PAD_C * HID_C * 2);
    // --- aliases onto scratch (sequential lifetimes, stream-ordered):
    uint2* buckets = (uint2*)scratch;                             // CSR build
    unsigned char* ta = (unsigned char*)scratch;                  // 3.2 MB fp8 table
    unsigned char* tb = (unsigned char*)(scratch + (size_t)N_NODES * 64); // 3.2 MB

    hipMemsetAsync(bfill, 0, (size_t)NBUCK * 4, stream);
    hipMemsetAsync(amax, 0, 64, stream);

    // K1: scatter + transpose_w1 + pad_w2 (independent, one launch)
    prep_fused<<<PHB_BLOCKS + TW_BLOCKS + PW_BLOCKS, 256, 0, stream>>>(
        erow, ecol, ew, bfill, buckets, W1, Wt, W2, b2, Wpt, bp);

    bucket_scan<<<1, 128, 0, stream>>>(bfill, bbase, rowptr);

    // K2: bucket_csr (98 blocks) overlapped with gemm (782 blocks) + amax[0]
    csr_gemm_fused<<<NBUCK + GEMM_BLOCKS, 256, 0, stream>>>(
        buckets, bfill, bbase, rowptr, edges,
        x, Wt, b1, Wpt, bp, h0b, amax);

    // Propagation: layer0 bf16-gather -> fp8 table; layers 1..8 fp8->fp8;
    // layer 9 fp8 -> log_softmax.
    const int prop_blocks = (N_NODES * 64 + 255) / 256;
    prop0<<<prop_blocks, 256, 0, stream>>>(rowptr, edges, h0b, amax, ta);
    unsigned char* cur = ta;
    unsigned char* nxt = tb;
    for (int l = 1; l <= 8; ++l) {
        prop_fp8<false><<<prop_blocks, 256, 0, stream>>>(rowptr, edges, cur, h0b,
                                                         amax, l, nxt, nullptr);
        unsigned char* t = cur; cur = nxt; nxt = t;
    }
    prop_fp8<true><<<prop_blocks, 256, 0, stream>>>(rowptr, edges, cur, h0b,
                                                    amax, 9, nullptr, out);
}